// Round 7
// baseline (520.484 us; speedup 1.0000x reference)
//
#include <hip/hip_runtime.h>
#include <hip/hip_bf16.h>

// BayesianKAN: 3 layers of  out[b,o] = sum_{i,k} B-spline-basis(x[b,i])[k] * cm[o,i,k]
// == GEMM (M=8192, N=OUT, K=IN*16) with generated A-operand, plus KL scalar.
// Numerics (validated R4): f16 MFMA; L0 2-term A-split, L1/L2 1-term.
// R5: B fragment-direct from pre-swizzled Bsw (global->VGPR, L3-resident);
//     A generated at 1x redundancy into LDS (256 thr cover 128 rows x 4 feats).
// R6 (REVERTED): per-lane register A-gen quadrupled VALU -> 82% VALUBusy, 2.3x slower.
// R7: double-buffered A + 1-iter reg prefetch of x/B, one barrier/kstep: 116us.
// R8 (REVERTED): lgkm-only barrier made it worse (125us) -> barrier drain is NOT
// the stall. Accounting: LDS pipe (shared per CU) = 190 nominal + 80 conflict
// cyc/wave-kstep; x8 resident waves ~= the 2343-cyc measured wall. LDS-pipe-bound.
// R9: kill the LDS write traffic. Build each 16-half A-segment in REGISTERS
// (R6's validated place_frag) and write 4x ds_write_b128 per thread instead of
// 4x zero-b128 + 8x data-dependent-address ds_write_u16 (the conflict source).
// Same values, same RTE rounding -> bit-identical output. Reads unchanged.

typedef __attribute__((ext_vector_type(8))) _Float16 f16x8;  // 8 f16 in 4 VGPRs
typedef __attribute__((ext_vector_type(4))) float float4v;   // MFMA accumulator
typedef unsigned short ushort_t;

__device__ __forceinline__ ushort_t f2h(float f) {
  _Float16 h = (_Float16)f;                 // RTE
  return *(ushort_t*)&h;
}
__device__ __forceinline__ float h2f(ushort_t u) {
  return (float)*(_Float16*)&u;
}

// Cubic B-spline (n_basis=16, clamped uniform knots: 13 cells of width 1/13).
__device__ __forceinline__ void bspline_w4(float x, int& k0, float w[4]) {
  const float XMAX = 1.0f - 1e-6f;
  float xe = fminf(fmaxf(x, 0.0f), XMAX);
  int cell = (int)(xe * 13.0f);
  cell = cell > 12 ? 12 : cell;
  k0 = cell;
  int j = cell + 3;                 // knot span, 3..15
  const float s = 1.0f / 13.0f;
  int cjm2 = max(j - 5, 0);
  int cjm1 = max(j - 4, 0);
  int cj   = j - 3;
  int cj1  = j - 2;
  int cj2  = min(j - 1, 13);
  int cj3  = min(j, 13);
  float tjm1 = cjm1 * s, tj = cj * s;
  float tjm2 = cjm2 * s;
  float tj1 = cj1 * s, tj2 = cj2 * s, tj3 = cj3 * s;
  float left1 = xe - tj, left2 = xe - tjm1, left3 = xe - tjm2;
  float right1 = tj1 - xe, right2 = tj2 - xe, right3 = tj3 - xe;
#define INV3(d) ((d) == 1 ? 13.0f : ((d) == 2 ? 6.5f : (13.0f / 3.0f)))
  float i10 = INV3(cj1 - cj);
  float i20 = INV3(cj1 - cjm1), i21 = INV3(cj2 - cj);
  float i30 = INV3(cj1 - cjm2), i31 = INV3(cj2 - cjm1), i32 = INV3(cj3 - cj);
#undef INV3
  float temp = i10;
  float N0 = right1 * temp;
  float N1 = left1 * temp;
  temp = N0 * i20;
  N0 = right1 * temp;
  float saved = left2 * temp;
  temp = N1 * i21;
  N1 = saved + right2 * temp;
  float N2 = left1 * temp;
  temp = N0 * i30;
  N0 = right1 * temp;
  saved = left3 * temp;
  temp = N1 * i31;
  N1 = saved + right2 * temp;
  saved = left2 * temp;
  temp = N2 * i32;
  N2 = saved + right3 * temp;
  float N3 = left1 * temp;
  w[0] = N0; w[1] = N1; w[2] = N2; w[3] = N3;
}

// Place packed taps (u01,u23 = w0..w3 as 4 f16) at half-offset k0 of a 16-half
// segment; return dwords [4h, 4h+4). Validated end-to-end in R6.
__device__ __forceinline__ f16x8 place_frag(unsigned u01, unsigned u23, int k0, int h) {
  const int p = k0 & 1;
  const unsigned X0 = p ? (u01 << 16) : u01;
  const unsigned X1 = p ? ((u01 >> 16) | (u23 << 16)) : u23;
  const unsigned X2 = p ? (u23 >> 16) : 0u;
  const int e = (k0 >> 1) - 4 * h;   // dword offset of X0 within this window
  union { unsigned u[4]; f16x8 v; } r;
#pragma unroll
  for (int j = 0; j < 4; ++j) {
    const int idx = j - e;
    unsigned t = (idx == 1) ? X1 : X0;
    t = (idx == 2) ? X2 : t;
    r.u[j] = ((unsigned)idx < 3u) ? t : 0u;
  }
  return r.v;
}

// Fused basis-gen + GEMM. Tile 128x128, BK=64 (4 feats x 16 basis), 256 thr =
// 4 waves 2x2, wave tile 64x64 (4x4 frags of f32_16x16x32_f16).
// A staged via double-buffered LDS (register-built rows, b128 writes only);
// B fragment-direct global->VGPR, prefetched. blockIdx.z = split-K.
template <bool SPLIT_A>
__global__ __launch_bounds__(256, 2) void kan_layer(
    const float* __restrict__ act, const ushort_t* __restrict__ Bsw,
    float* __restrict__ outp, int IN, int OUT) {
  const int K = IN * 16;
  const int KC = K >> 3;                             // k-chunks of 8
  __shared__ ushort_t Ah[2][128 * 72];               // stride 72: +8 pad
  __shared__ ushort_t Al[SPLIT_A ? 2 : 1][SPLIT_A ? 128 * 72 : 1];

  const int tid = threadIdx.x;
  const int lane = tid & 63;
  const int wv = tid >> 6;
  const int wm = wv >> 1, wn = wv & 1;    // 2x2 wave grid
  const int quad = lane >> 4, l15 = lane & 15;
  const int b0 = blockIdx.x * 128;
  const int n0 = blockIdx.y * 128;
  const int tbase = (n0 >> 4) + wn * 4;   // B row-tile base for this wave

  float4v acc[4][4];
#pragma unroll
  for (int a = 0; a < 4; a++)
#pragma unroll
    for (int b = 0; b < 4; b++) acc[a][b] = (float4v)0.0f;

  const int gm = tid >> 1;            // basis-gen: row 0..127
  const int gip = (tid & 1) * 2;      // feat-pair base (0 or 2) of 4 per kstep
  const float* xrow = &act[(size_t)(b0 + gm) * IN + gip];

  const ushort_t* bbase[4];
#pragma unroll
  for (int nt = 0; nt < 4; ++nt)
    bbase[nt] = Bsw + (size_t)(tbase + nt) * KC * 128 + lane * 8;

  const int nsteps = K / 64;
  const int chunk = nsteps / gridDim.z;  // always even (16 or 32)
  const int kbeg = blockIdx.z * chunk;
  const int kend = kbeg + chunk;
  const int klast = kend - 1;

// ---- eval splines (VALU), build segments in regs, 4x ds_write_b128 ----
#define EVAL_WRITE(BUF, XV)                                                   \
  {                                                                           \
    int k0a, k0b; float wa[4], wb[4];                                         \
    bspline_w4((XV).x, k0a, wa);                                              \
    bspline_w4((XV).y, k0b, wb);                                              \
    unsigned a01 = (unsigned)f2h(wa[0]) | ((unsigned)f2h(wa[1]) << 16);       \
    unsigned a23 = (unsigned)f2h(wa[2]) | ((unsigned)f2h(wa[3]) << 16);       \
    unsigned b01 = (unsigned)f2h(wb[0]) | ((unsigned)f2h(wb[1]) << 16);       \
    unsigned b23 = (unsigned)f2h(wb[2]) | ((unsigned)f2h(wb[3]) << 16);       \
    f16x8* arow = (f16x8*)&Ah[BUF][gm * 72 + gip * 16];                       \
    arow[0] = place_frag(a01, a23, k0a, 0);                                   \
    arow[1] = place_frag(a01, a23, k0a, 1);                                   \
    arow[2] = place_frag(b01, b23, k0b, 0);                                   \
    arow[3] = place_frag(b01, b23, k0b, 1);                                   \
    if (SPLIT_A) {                                                            \
      unsigned la01 = (unsigned)f2h(wa[0] - h2f(f2h(wa[0]))) |                \
                      ((unsigned)f2h(wa[1] - h2f(f2h(wa[1]))) << 16);         \
      unsigned la23 = (unsigned)f2h(wa[2] - h2f(f2h(wa[2]))) |                \
                      ((unsigned)f2h(wa[3] - h2f(f2h(wa[3]))) << 16);         \
      unsigned lb01 = (unsigned)f2h(wb[0] - h2f(f2h(wb[0]))) |                \
                      ((unsigned)f2h(wb[1] - h2f(f2h(wb[1]))) << 16);         \
      unsigned lb23 = (unsigned)f2h(wb[2] - h2f(f2h(wb[2]))) |                \
                      ((unsigned)f2h(wb[3] - h2f(f2h(wb[3]))) << 16);         \
      f16x8* lrow = (f16x8*)&Al[BUF][gm * 72 + gip * 16];                     \
      lrow[0] = place_frag(la01, la23, k0a, 0);                               \
      lrow[1] = place_frag(la01, la23, k0a, 1);                               \
      lrow[2] = place_frag(lb01, lb23, k0b, 0);                               \
      lrow[3] = place_frag(lb01, lb23, k0b, 1);                               \
    }                                                                         \
  }

// ---- ds_read A-frags from buffer BUF, MFMA against B-frag regs BF ----
#define MFMA_STEP(BUF, BF)                                                    \
  _Pragma("unroll")                                                           \
  for (int ks = 0; ks < 2; ++ks) {                                            \
    f16x8 ahf[4], alf[4];                                                     \
    _Pragma("unroll")                                                         \
    for (int mt = 0; mt < 4; ++mt) {                                          \
      int off = (wm * 64 + mt * 16 + l15) * 72 + ks * 32 + quad * 8;          \
      ahf[mt] = *(const f16x8*)&Ah[BUF][off];                                 \
      if (SPLIT_A) alf[mt] = *(const f16x8*)&Al[BUF][off];                    \
    }                                                                         \
    _Pragma("unroll")                                                         \
    for (int mt = 0; mt < 4; ++mt)                                            \
      _Pragma("unroll")                                                       \
      for (int nt = 0; nt < 4; ++nt) {                                        \
        if (SPLIT_A)                                                          \
          acc[mt][nt] = __builtin_amdgcn_mfma_f32_16x16x32_f16(               \
              alf[mt], (BF)[ks][nt], acc[mt][nt], 0, 0, 0);                   \
        acc[mt][nt] = __builtin_amdgcn_mfma_f32_16x16x32_f16(                 \
            ahf[mt], (BF)[ks][nt], acc[mt][nt], 0, 0, 0);                     \
      }                                                                       \
  }

// ---- one pipelined k-step (R7 structure) ----
// entering: Ah[CUR] = A[KS]; BFC = B[KS]; XVC = x[KS+1] (regs).
// issue B[KS+1]->BFN, x[KS+2]->XVN; MFMA; eval+write A[KS+1] -> Ah[CUR^1].
#define KSTEP_BODY(KS, CUR, BFC, BFN, XVC, XVN)                               \
  {                                                                           \
    const int kp1 = ((KS) + 1 <= klast) ? (KS) + 1 : klast;                   \
    const int kp2 = ((KS) + 2 <= klast) ? (KS) + 2 : klast;                   \
    _Pragma("unroll")                                                         \
    for (int ks = 0; ks < 2; ++ks)                                            \
      _Pragma("unroll")                                                       \
      for (int nt = 0; nt < 4; ++nt)                                          \
        BFN[ks][nt] =                                                         \
            *(const f16x8*)&bbase[nt][(size_t)kp1 * 1024 + ks * 512];         \
    XVN = *(const float2*)&xrow[kp2 * 4];                                     \
    MFMA_STEP(CUR, BFC);                                                      \
    EVAL_WRITE((CUR) ^ 1, XVC);                                               \
    __syncthreads();                                                          \
  }

  // ---- prologue: A[kbeg] into Ah[0]; B[kbeg] + x[kbeg+1] into regs ----
  f16x8 bf0[2][4], bf1[2][4];
#pragma unroll
  for (int ks = 0; ks < 2; ++ks)
#pragma unroll
    for (int nt = 0; nt < 4; ++nt)
      bf0[ks][nt] = *(const f16x8*)&bbase[nt][(size_t)kbeg * 1024 + ks * 512];
  float2 xvP = *(const float2*)&xrow[kbeg * 4];
  float2 xv0 = *(const float2*)&xrow[((kbeg + 1 <= klast) ? kbeg + 1 : klast) * 4];
  float2 xv1;
  EVAL_WRITE(0, xvP);
  __syncthreads();

  for (int k = kbeg; k < kend; k += 2) {
    KSTEP_BODY(k,     0, bf0, bf1, xv0, xv1);
    KSTEP_BODY(k + 1, 1, bf1, bf0, xv1, xv0);
  }

#undef KSTEP_BODY
#undef MFMA_STEP
#undef EVAL_WRITE

  // ---- epilogue: C/D layout col=lane&15, row=quad*4+reg; split-K atomics ----
#pragma unroll
  for (int mt = 0; mt < 4; ++mt)
#pragma unroll
    for (int nt = 0; nt < 4; ++nt) {
      int col = n0 + wn * 64 + nt * 16 + l15;
#pragma unroll
      for (int r = 0; r < 4; ++r) {
        int row = b0 + wm * 64 + mt * 16 + quad * 4 + r;
        atomicAdd(&outp[(size_t)row * OUT + col], acc[mt][nt][r]);
      }
    }
}

// KL accumulation + f16 conversion + fragment-order swizzle, one pass over cm/lv.
// Group = 8 consecutive k of one output row o: dest Bsw[o/16][k/8][o%16][8].
__global__ __launch_bounds__(256) void kl_convert(
    const float* __restrict__ cm, const float* __restrict__ lv,
    ushort_t* __restrict__ bsw, int G /* = IN*2 groups per row */,
    long long ngroups, float* __restrict__ klout) {
  long long i = (long long)blockIdx.x * blockDim.x + threadIdx.x;
  const long long stride = (long long)gridDim.x * blockDim.x;
  float s = 0.0f;
  for (; i < ngroups; i += stride) {
    int o = (int)(i / G);
    int kc = (int)(i - (long long)o * G);
    const float* cp = &cm[i * 8];
    const float* lp = &lv[i * 8];
    unsigned pk[4];
#pragma unroll
    for (int t = 0; t < 4; ++t) {
      float c0 = cp[2 * t], c1 = cp[2 * t + 1];
      float l0 = lp[2 * t], l1 = lp[2 * t + 1];
      pk[t] = (unsigned)f2h(c0) | ((unsigned)f2h(c1) << 16);
      s += 0.5f * (__expf(l0) + c0 * c0 - 1.0f - l0);
      s += 0.5f * (__expf(l1) + c1 * c1 - 1.0f - l1);
    }
    uint4 v; v.x = pk[0]; v.y = pk[1]; v.z = pk[2]; v.w = pk[3];
    size_t doff = (((size_t)(o >> 4) * G + kc) * 16 + (o & 15)) * 8;
    *(uint4*)&bsw[doff] = v;
  }
#pragma unroll
  for (int off = 32; off > 0; off >>= 1) s += __shfl_down(s, off, 64);
  __shared__ float red[4];
  int wv = threadIdx.x >> 6;
  if ((threadIdx.x & 63) == 0) red[wv] = s;
  __syncthreads();
  if (threadIdx.x == 0)
    atomicAdd(klout, red[0] + red[1] + red[2] + red[3]);
}

extern "C" void kernel_launch(void* const* d_in, const int* in_sizes, int n_in,
                              void* d_out, int out_size, void* d_ws, size_t ws_size,
                              hipStream_t stream) {
  const float* x   = (const float*)d_in[0];
  const float* cm0 = (const float*)d_in[1];
  const float* lv0 = (const float*)d_in[2];
  const float* cm1 = (const float*)d_in[3];
  const float* lv1 = (const float*)d_in[4];
  const float* cm2 = (const float*)d_in[5];
  const float* lv2 = (const float*)d_in[6];

  float* out = (float*)d_out;                       // (8192*256) out + 1 KL
  float* klp = out + (size_t)8192 * 256;

  // ws layout (48 MB): acts 2x16MB, swizzled f16 weights 16MB
  char* ws = (char*)d_ws;
  float*    act1 = (float*)(ws);                               // 8192*512 f32
  float*    act2 = (float*)(ws + ((size_t)16 << 20));          // 8192*512 f32
  ushort_t* b0sw = (ushort_t*)(ws + ((size_t)32 << 20));       // 512*256*16 f16
  ushort_t* b1sw = (ushort_t*)(ws + ((size_t)36 << 20));       // 512*512*16 f16
  ushort_t* b2sw = (ushort_t*)(ws + ((size_t)44 << 20));       // 256*512*16 f16

  // zero split-K accumulation targets (act1+act2 contiguous; d_out incl KL)
  hipMemsetAsync(ws, 0, (size_t)32 << 20, stream);
  hipMemsetAsync(d_out, 0, (size_t)out_size * sizeof(float), stream);

  kl_convert<<<2048, 256, 0, stream>>>(cm0, lv0, b0sw, 256 * 2, 512LL * 256 * 2, klp);
  kl_convert<<<2048, 256, 0, stream>>>(cm1, lv1, b1sw, 512 * 2, 512LL * 512 * 2, klp);
  kl_convert<<<2048, 256, 0, stream>>>(cm2, lv2, b2sw, 512 * 2, 256LL * 512 * 2, klp);

  // 1024 blocks/layer; LDS: L0 73728 B, L1/L2 36864 B (double-buffered A)
  kan_layer<true ><<<dim3(64, 4, 4), 256, 0, stream>>>(x,    b0sw, act1, 256, 512);
  kan_layer<false><<<dim3(64, 4, 4), 256, 0, stream>>>(act1, b1sw, act2, 512, 512);
  kan_layer<false><<<dim3(64, 2, 8), 256, 0, stream>>>(act2, b2sw, out,  512, 256);
}

// Round 15
// 517.341 us; speedup vs baseline: 1.0061x; 1.0061x over previous
//
#include <hip/hip_runtime.h>
#include <hip/hip_bf16.h>

// BayesianKAN: 3 layers of  out[b,o] = sum_{i,k} B-spline-basis(x[b,i])[k] * cm[o,i,k]
// == GEMM (M=8192, N=OUT, K=IN*16) with generated A-operand, plus KL scalar.
// Numerics (validated R4): f16 MFMA; L0 2-term A-split, L1/L2 1-term.
// R5: B fragment-direct from pre-swizzled Bsw (global->VGPR, L3-resident);
//     A generated at 1x redundancy into LDS (256 thr cover 128 rows x 4 feats).
// R6 (REVERTED): per-lane register A-gen quadrupled VALU -> 82% VALUBusy, 2.3x slower.
// R7: double-buffered A + 1-iter reg prefetch of x/B, one barrier/kstep: 116us.
// R8 (REVERTED): lgkm-only barrier worse (125us) -> barrier vmem drain not the stall.
// R9 (REVERTED): reg-built A segments (b128-only writes) cut conflicts 2.5x but
// added ~100 VALU instr/thread/kstep -> L1 140us. KEY MODEL from R7/R9 pair:
// wall = VALU + X (MFMA-time constant 28.5us; VALU delta moved wall 1:1).
// VALU is SERIAL with the stall X because only 2 waves/SIMD are resident.
// R10: occupancy 2->3 blocks/CU. Same R7 code; __launch_bounds__(256,3).
// 140 unified regs <= 170 budget (no spill); LDS 3x36864=108KB fits (L1/L2).
// Third wave/SIMD lets eval run under another block's barrier/ds-wait.

typedef __attribute__((ext_vector_type(8))) _Float16 f16x8;  // 8 f16 in 4 VGPRs
typedef __attribute__((ext_vector_type(4))) float float4v;   // MFMA accumulator
typedef unsigned short ushort_t;

__device__ __forceinline__ ushort_t f2h(float f) {
  _Float16 h = (_Float16)f;                 // RTE
  return *(ushort_t*)&h;
}
__device__ __forceinline__ float h2f(ushort_t u) {
  return (float)*(_Float16*)&u;
}

// Cubic B-spline (n_basis=16, clamped uniform knots: 13 cells of width 1/13).
__device__ __forceinline__ void bspline_w4(float x, int& k0, float w[4]) {
  const float XMAX = 1.0f - 1e-6f;
  float xe = fminf(fmaxf(x, 0.0f), XMAX);
  int cell = (int)(xe * 13.0f);
  cell = cell > 12 ? 12 : cell;
  k0 = cell;
  int j = cell + 3;                 // knot span, 3..15
  const float s = 1.0f / 13.0f;
  int cjm2 = max(j - 5, 0);
  int cjm1 = max(j - 4, 0);
  int cj   = j - 3;
  int cj1  = j - 2;
  int cj2  = min(j - 1, 13);
  int cj3  = min(j, 13);
  float tjm1 = cjm1 * s, tj = cj * s;
  float tjm2 = cjm2 * s;
  float tj1 = cj1 * s, tj2 = cj2 * s, tj3 = cj3 * s;
  float left1 = xe - tj, left2 = xe - tjm1, left3 = xe - tjm2;
  float right1 = tj1 - xe, right2 = tj2 - xe, right3 = tj3 - xe;
#define INV3(d) ((d) == 1 ? 13.0f : ((d) == 2 ? 6.5f : (13.0f / 3.0f)))
  float i10 = INV3(cj1 - cj);
  float i20 = INV3(cj1 - cjm1), i21 = INV3(cj2 - cj);
  float i30 = INV3(cj1 - cjm2), i31 = INV3(cj2 - cjm1), i32 = INV3(cj3 - cj);
#undef INV3
  float temp = i10;
  float N0 = right1 * temp;
  float N1 = left1 * temp;
  temp = N0 * i20;
  N0 = right1 * temp;
  float saved = left2 * temp;
  temp = N1 * i21;
  N1 = saved + right2 * temp;
  float N2 = left1 * temp;
  temp = N0 * i30;
  N0 = right1 * temp;
  saved = left3 * temp;
  temp = N1 * i31;
  N1 = saved + right2 * temp;
  saved = left2 * temp;
  temp = N2 * i32;
  N2 = saved + right3 * temp;
  float N3 = left1 * temp;
  w[0] = N0; w[1] = N1; w[2] = N2; w[3] = N3;
}

// Fused basis-gen + GEMM. Tile 128x128, BK=64 (4 feats x 16 basis), 256 thr =
// 4 waves 2x2, wave tile 64x64 (4x4 frags of f32_16x16x32_f16).
// A staged via double-buffered LDS; B fragment-direct global->VGPR, prefetched.
// blockIdx.z = split-K; partials atomicAdd into pre-zeroed outp.
template <bool SPLIT_A>
__global__ __launch_bounds__(256, 3) void kan_layer(
    const float* __restrict__ act, const ushort_t* __restrict__ Bsw,
    float* __restrict__ outp, int IN, int OUT) {
  const int K = IN * 16;
  const int KC = K >> 3;                             // k-chunks of 8
  __shared__ ushort_t Ah[2][128 * 72];               // stride 72: +8 pad
  __shared__ ushort_t Al[SPLIT_A ? 2 : 1][SPLIT_A ? 128 * 72 : 1];

  const int tid = threadIdx.x;
  const int lane = tid & 63;
  const int wv = tid >> 6;
  const int wm = wv >> 1, wn = wv & 1;    // 2x2 wave grid
  const int quad = lane >> 4, l15 = lane & 15;
  const int b0 = blockIdx.x * 128;
  const int n0 = blockIdx.y * 128;
  const int tbase = (n0 >> 4) + wn * 4;   // B row-tile base for this wave

  float4v acc[4][4];
#pragma unroll
  for (int a = 0; a < 4; a++)
#pragma unroll
    for (int b = 0; b < 4; b++) acc[a][b] = (float4v)0.0f;

  const int gm = tid >> 1;            // basis-gen: row 0..127
  const int gip = (tid & 1) * 2;      // feat-pair base (0 or 2) of 4 per kstep
  const float* xrow = &act[(size_t)(b0 + gm) * IN + gip];

  const ushort_t* bbase[4];
#pragma unroll
  for (int nt = 0; nt < 4; ++nt)
    bbase[nt] = Bsw + (size_t)(tbase + nt) * KC * 128 + lane * 8;

  const int nsteps = K / 64;
  const int chunk = nsteps / gridDim.z;  // always even (16 or 32)
  const int kbeg = blockIdx.z * chunk;
  const int kend = kbeg + chunk;
  const int klast = kend - 1;

// ---- eval splines (VALU) from regs, write A rows into buffer BUF ----
#define EVAL_WRITE(BUF, XV)                                                   \
  {                                                                           \
    int k0a, k0b; float wa[4], wb[4];                                         \
    bspline_w4((XV).x, k0a, wa);                                              \
    bspline_w4((XV).y, k0b, wb);                                              \
    uint4 z4; z4.x = z4.y = z4.z = z4.w = 0u;                                 \
    ushort_t* arow_h = &Ah[BUF][gm * 72 + gip * 16];                          \
    ((uint4*)arow_h)[0] = z4; ((uint4*)arow_h)[1] = z4;                       \
    ((uint4*)arow_h)[2] = z4; ((uint4*)arow_h)[3] = z4;                       \
    _Pragma("unroll")                                                         \
    for (int t = 0; t < 4; ++t) {                                             \
      arow_h[k0a + t] = f2h(wa[t]);                                           \
      arow_h[16 + k0b + t] = f2h(wb[t]);                                      \
    }                                                                         \
    if (SPLIT_A) {                                                            \
      ushort_t* arow_l = &Al[BUF][gm * 72 + gip * 16];                        \
      ((uint4*)arow_l)[0] = z4; ((uint4*)arow_l)[1] = z4;                     \
      ((uint4*)arow_l)[2] = z4; ((uint4*)arow_l)[3] = z4;                     \
      _Pragma("unroll")                                                       \
      for (int t = 0; t < 4; ++t) {                                           \
        arow_l[k0a + t] = f2h(wa[t] - h2f(f2h(wa[t])));                       \
        arow_l[16 + k0b + t] = f2h(wb[t] - h2f(f2h(wb[t])));                  \
      }                                                                       \
    }                                                                         \
  }

// ---- ds_read A-frags from buffer BUF, MFMA against B-frag regs BF ----
#define MFMA_STEP(BUF, BF)                                                    \
  _Pragma("unroll")                                                           \
  for (int ks = 0; ks < 2; ++ks) {                                            \
    f16x8 ahf[4], alf[4];                                                     \
    _Pragma("unroll")                                                         \
    for (int mt = 0; mt < 4; ++mt) {                                          \
      int off = (wm * 64 + mt * 16 + l15) * 72 + ks * 32 + quad * 8;          \
      ahf[mt] = *(const f16x8*)&Ah[BUF][off];                                 \
      if (SPLIT_A) alf[mt] = *(const f16x8*)&Al[BUF][off];                    \
    }                                                                         \
    _Pragma("unroll")                                                         \
    for (int mt = 0; mt < 4; ++mt)                                            \
      _Pragma("unroll")                                                       \
      for (int nt = 0; nt < 4; ++nt) {                                        \
        if (SPLIT_A)                                                          \
          acc[mt][nt] = __builtin_amdgcn_mfma_f32_16x16x32_f16(               \
              alf[mt], (BF)[ks][nt], acc[mt][nt], 0, 0, 0);                   \
        acc[mt][nt] = __builtin_amdgcn_mfma_f32_16x16x32_f16(                 \
            ahf[mt], (BF)[ks][nt], acc[mt][nt], 0, 0, 0);                     \
      }                                                                       \
  }

// ---- one pipelined k-step ----
// entering: Ah[CUR] = A[KS]; BFC = B[KS]; XVC = x[KS+1] (regs).
// issue B[KS+1]->BFN, x[KS+2]->XVN; MFMA; eval+write A[KS+1] -> Ah[CUR^1].
#define KSTEP_BODY(KS, CUR, BFC, BFN, XVC, XVN)                               \
  {                                                                           \
    const int kp1 = ((KS) + 1 <= klast) ? (KS) + 1 : klast;                   \
    const int kp2 = ((KS) + 2 <= klast) ? (KS) + 2 : klast;                   \
    _Pragma("unroll")                                                         \
    for (int ks = 0; ks < 2; ++ks)                                            \
      _Pragma("unroll")                                                       \
      for (int nt = 0; nt < 4; ++nt)                                          \
        BFN[ks][nt] =                                                         \
            *(const f16x8*)&bbase[nt][(size_t)kp1 * 1024 + ks * 512];         \
    XVN = *(const float2*)&xrow[kp2 * 4];                                     \
    MFMA_STEP(CUR, BFC);                                                      \
    EVAL_WRITE((CUR) ^ 1, XVC);                                               \
    __syncthreads();                                                          \
  }

  // ---- prologue: A[kbeg] into Ah[0]; B[kbeg] + x[kbeg+1] into regs ----
  f16x8 bf0[2][4], bf1[2][4];
#pragma unroll
  for (int ks = 0; ks < 2; ++ks)
#pragma unroll
    for (int nt = 0; nt < 4; ++nt)
      bf0[ks][nt] = *(const f16x8*)&bbase[nt][(size_t)kbeg * 1024 + ks * 512];
  float2 xvP = *(const float2*)&xrow[kbeg * 4];
  float2 xv0 = *(const float2*)&xrow[((kbeg + 1 <= klast) ? kbeg + 1 : klast) * 4];
  float2 xv1;
  EVAL_WRITE(0, xvP);
  __syncthreads();

  for (int k = kbeg; k < kend; k += 2) {
    KSTEP_BODY(k,     0, bf0, bf1, xv0, xv1);
    KSTEP_BODY(k + 1, 1, bf1, bf0, xv1, xv0);
  }

#undef KSTEP_BODY
#undef MFMA_STEP
#undef EVAL_WRITE

  // ---- epilogue: C/D layout col=lane&15, row=quad*4+reg; split-K atomics ----
#pragma unroll
  for (int mt = 0; mt < 4; ++mt)
#pragma unroll
    for (int nt = 0; nt < 4; ++nt) {
      int col = n0 + wn * 64 + nt * 16 + l15;
#pragma unroll
      for (int r = 0; r < 4; ++r) {
        int row = b0 + wm * 64 + mt * 16 + quad * 4 + r;
        atomicAdd(&outp[(size_t)row * OUT + col], acc[mt][nt][r]);
      }
    }
}

// KL accumulation + f16 conversion + fragment-order swizzle, one pass over cm/lv.
// Group = 8 consecutive k of one output row o: dest Bsw[o/16][k/8][o%16][8].
__global__ __launch_bounds__(256) void kl_convert(
    const float* __restrict__ cm, const float* __restrict__ lv,
    ushort_t* __restrict__ bsw, int G /* = IN*2 groups per row */,
    long long ngroups, float* __restrict__ klout) {
  long long i = (long long)blockIdx.x * blockDim.x + threadIdx.x;
  const long long stride = (long long)gridDim.x * blockDim.x;
  float s = 0.0f;
  for (; i < ngroups; i += stride) {
    int o = (int)(i / G);
    int kc = (int)(i - (long long)o * G);
    const float* cp = &cm[i * 8];
    const float* lp = &lv[i * 8];
    unsigned pk[4];
#pragma unroll
    for (int t = 0; t < 4; ++t) {
      float c0 = cp[2 * t], c1 = cp[2 * t + 1];
      float l0 = lp[2 * t], l1 = lp[2 * t + 1];
      pk[t] = (unsigned)f2h(c0) | ((unsigned)f2h(c1) << 16);
      s += 0.5f * (__expf(l0) + c0 * c0 - 1.0f - l0);
      s += 0.5f * (__expf(l1) + c1 * c1 - 1.0f - l1);
    }
    uint4 v; v.x = pk[0]; v.y = pk[1]; v.z = pk[2]; v.w = pk[3];
    size_t doff = (((size_t)(o >> 4) * G + kc) * 16 + (o & 15)) * 8;
    *(uint4*)&bsw[doff] = v;
  }
#pragma unroll
  for (int off = 32; off > 0; off >>= 1) s += __shfl_down(s, off, 64);
  __shared__ float red[4];
  int wv = threadIdx.x >> 6;
  if ((threadIdx.x & 63) == 0) red[wv] = s;
  __syncthreads();
  if (threadIdx.x == 0)
    atomicAdd(klout, red[0] + red[1] + red[2] + red[3]);
}

extern "C" void kernel_launch(void* const* d_in, const int* in_sizes, int n_in,
                              void* d_out, int out_size, void* d_ws, size_t ws_size,
                              hipStream_t stream) {
  const float* x   = (const float*)d_in[0];
  const float* cm0 = (const float*)d_in[1];
  const float* lv0 = (const float*)d_in[2];
  const float* cm1 = (const float*)d_in[3];
  const float* lv1 = (const float*)d_in[4];
  const float* cm2 = (const float*)d_in[5];
  const float* lv2 = (const float*)d_in[6];

  float* out = (float*)d_out;                       // (8192*256) out + 1 KL
  float* klp = out + (size_t)8192 * 256;

  // ws layout (48 MB): acts 2x16MB, swizzled f16 weights 16MB
  char* ws = (char*)d_ws;
  float*    act1 = (float*)(ws);                               // 8192*512 f32
  float*    act2 = (float*)(ws + ((size_t)16 << 20));          // 8192*512 f32
  ushort_t* b0sw = (ushort_t*)(ws + ((size_t)32 << 20));       // 512*256*16 f16
  ushort_t* b1sw = (ushort_t*)(ws + ((size_t)36 << 20));       // 512*512*16 f16
  ushort_t* b2sw = (ushort_t*)(ws + ((size_t)44 << 20));       // 256*512*16 f16

  // zero split-K accumulation targets (act1+act2 contiguous; d_out incl KL)
  hipMemsetAsync(ws, 0, (size_t)32 << 20, stream);
  hipMemsetAsync(d_out, 0, (size_t)out_size * sizeof(float), stream);

  kl_convert<<<2048, 256, 0, stream>>>(cm0, lv0, b0sw, 256 * 2, 512LL * 256 * 2, klp);
  kl_convert<<<2048, 256, 0, stream>>>(cm1, lv1, b1sw, 512 * 2, 512LL * 512 * 2, klp);
  kl_convert<<<2048, 256, 0, stream>>>(cm2, lv2, b2sw, 512 * 2, 256LL * 512 * 2, klp);

  // 1024 blocks/layer; LDS: L0 73728 B (2 blk/CU), L1/L2 36864 B (3 blk/CU)
  kan_layer<true ><<<dim3(64, 4, 4), 256, 0, stream>>>(x,    b0sw, act1, 256, 512);
  kan_layer<false><<<dim3(64, 4, 4), 256, 0, stream>>>(act1, b1sw, act2, 512, 512);
  kan_layer<false><<<dim3(64, 2, 8), 256, 0, stream>>>(act2, b2sw, out,  512, 256);
}

// Round 20
// 461.472 us; speedup vs baseline: 1.1279x; 1.1211x over previous
//
#include <hip/hip_runtime.h>
#include <hip/hip_bf16.h>

// BayesianKAN: 3 layers of  out[b,o] = sum_{i,k} B-spline-basis(x[b,i])[k] * cm[o,i,k]
// == GEMM (M=8192, N=OUT, K=IN*16) with generated A-operand, plus KL scalar.
// Numerics (validated R4): f16 MFMA; L0 2-term A-split, L1/L2 1-term.
// R5: B fragment-direct from pre-swizzled Bsw; A gen 1x redundancy into LDS.
// R6 (REV): per-lane reg A-gen 4x VALU -> 2.3x slower. R7: dbuf A + reg
// prefetch, 1 barrier/kstep: 116us L1, 482 total (BEST). R8 (REV): lgkm-only
// barrier worse. R9 (REV): reg-built A rows: conflicts -2.5x but +VALU -> 140us.
// MODEL: wall = VALU + X; nothing saturated (LDS ~50%, VALU 38%, MFMA 24%) ->
// latency-bound, needs TLP. R10 (REV): launch_bounds(256,3) made the ALLOCATOR
// inflate VGPR 76->132 (196 unified > 170) -> L0 occupancy 11%, total 517.
// R11: occupancy via RESOURCE DIET. Wave tile 64x32 (acc 32, bf-dbuf 32,
// A-tile halves: 18432/36864 LDS) + launch_bounds(256,4) caps unified regs at
// 128 -> 4 waves/SIMD. Eval stays 1x (4 thr/row x 1 feat; per-wave VALU
// halves). Per-output MFMA order unchanged -> same absmax. B re-read 2x by
// row-blocks but Bsw is L3-resident (HBM FETCH unchanged).

typedef __attribute__((ext_vector_type(8))) _Float16 f16x8;  // 8 f16 in 4 VGPRs
typedef __attribute__((ext_vector_type(4))) float float4v;   // MFMA accumulator
typedef unsigned short ushort_t;

__device__ __forceinline__ ushort_t f2h(float f) {
  _Float16 h = (_Float16)f;                 // RTE
  return *(ushort_t*)&h;
}
__device__ __forceinline__ float h2f(ushort_t u) {
  return (float)*(_Float16*)&u;
}

// Cubic B-spline (n_basis=16, clamped uniform knots: 13 cells of width 1/13).
__device__ __forceinline__ void bspline_w4(float x, int& k0, float w[4]) {
  const float XMAX = 1.0f - 1e-6f;
  float xe = fminf(fmaxf(x, 0.0f), XMAX);
  int cell = (int)(xe * 13.0f);
  cell = cell > 12 ? 12 : cell;
  k0 = cell;
  int j = cell + 3;                 // knot span, 3..15
  const float s = 1.0f / 13.0f;
  int cjm2 = max(j - 5, 0);
  int cjm1 = max(j - 4, 0);
  int cj   = j - 3;
  int cj1  = j - 2;
  int cj2  = min(j - 1, 13);
  int cj3  = min(j, 13);
  float tjm1 = cjm1 * s, tj = cj * s;
  float tjm2 = cjm2 * s;
  float tj1 = cj1 * s, tj2 = cj2 * s, tj3 = cj3 * s;
  float left1 = xe - tj, left2 = xe - tjm1, left3 = xe - tjm2;
  float right1 = tj1 - xe, right2 = tj2 - xe, right3 = tj3 - xe;
#define INV3(d) ((d) == 1 ? 13.0f : ((d) == 2 ? 6.5f : (13.0f / 3.0f)))
  float i10 = INV3(cj1 - cj);
  float i20 = INV3(cj1 - cjm1), i21 = INV3(cj2 - cj);
  float i30 = INV3(cj1 - cjm2), i31 = INV3(cj2 - cjm1), i32 = INV3(cj3 - cj);
#undef INV3
  float temp = i10;
  float N0 = right1 * temp;
  float N1 = left1 * temp;
  temp = N0 * i20;
  N0 = right1 * temp;
  float saved = left2 * temp;
  temp = N1 * i21;
  N1 = saved + right2 * temp;
  float N2 = left1 * temp;
  temp = N0 * i30;
  N0 = right1 * temp;
  saved = left3 * temp;
  temp = N1 * i31;
  N1 = saved + right2 * temp;
  saved = left2 * temp;
  temp = N2 * i32;
  N2 = saved + right3 * temp;
  float N3 = left1 * temp;
  w[0] = N0; w[1] = N1; w[2] = N2; w[3] = N3;
}

// Fused basis-gen + GEMM. Tile 64x128, BK=64 (4 feats x 16 basis), 256 thr =
// 4 waves 1x4, wave tile 64x32 (4x2 frags of f32_16x16x32_f16).
// A staged via double-buffered LDS; B fragment-direct global->VGPR, prefetched.
// blockIdx.z = split-K; partials atomicAdd into pre-zeroed outp.
template <bool SPLIT_A>
__global__ __launch_bounds__(256, 4) void kan_layer(
    const float* __restrict__ act, const ushort_t* __restrict__ Bsw,
    float* __restrict__ outp, int IN, int OUT) {
  const int K = IN * 16;
  const int KC = K >> 3;                             // k-chunks of 8
  __shared__ ushort_t Ah[2][64 * 72];                // stride 72: +8 pad
  __shared__ ushort_t Al[SPLIT_A ? 2 : 1][SPLIT_A ? 64 * 72 : 1];

  const int tid = threadIdx.x;
  const int lane = tid & 63;
  const int wn = tid >> 6;                // 1x4 wave grid (wm == 0)
  const int quad = lane >> 4, l15 = lane & 15;
  const int b0 = blockIdx.x * 64;
  const int n0 = blockIdx.y * 128;
  const int tbase = (n0 >> 4) + wn * 2;   // B row-tile base for this wave

  float4v acc[4][2];
#pragma unroll
  for (int a = 0; a < 4; a++)
#pragma unroll
    for (int b = 0; b < 2; b++) acc[a][b] = (float4v)0.0f;

  const int gm = tid >> 2;            // basis-gen: row 0..63
  const int gf = tid & 3;             // feat 0..3 of this kstep
  const float* xrow = &act[(size_t)(b0 + gm) * IN + gf];

  const ushort_t* bbase[2];
#pragma unroll
  for (int nt = 0; nt < 2; ++nt)
    bbase[nt] = Bsw + (size_t)(tbase + nt) * KC * 128 + lane * 8;

  const int nsteps = K / 64;
  const int chunk = nsteps / gridDim.z;  // always even (16 or 32)
  const int kbeg = blockIdx.z * chunk;
  const int kend = kbeg + chunk;
  const int klast = kend - 1;

// ---- eval spline (VALU) from reg, write one 16-half A segment into BUF ----
#define EVAL_WRITE(BUF, XS)                                                   \
  {                                                                           \
    int k0a; float wa[4];                                                     \
    bspline_w4(XS, k0a, wa);                                                  \
    uint4 z4; z4.x = z4.y = z4.z = z4.w = 0u;                                 \
    ushort_t* arow_h = &Ah[BUF][gm * 72 + gf * 16];                           \
    ((uint4*)arow_h)[0] = z4; ((uint4*)arow_h)[1] = z4;                       \
    _Pragma("unroll")                                                         \
    for (int t = 0; t < 4; ++t) arow_h[k0a + t] = f2h(wa[t]);                 \
    if (SPLIT_A) {                                                            \
      ushort_t* arow_l = &Al[BUF][gm * 72 + gf * 16];                         \
      ((uint4*)arow_l)[0] = z4; ((uint4*)arow_l)[1] = z4;                     \
      _Pragma("unroll")                                                       \
      for (int t = 0; t < 4; ++t)                                             \
        arow_l[k0a + t] = f2h(wa[t] - h2f(f2h(wa[t])));                       \
    }                                                                         \
  }

// ---- ds_read A-frags from buffer BUF, MFMA against B-frag regs BF ----
#define MFMA_STEP(BUF, BF)                                                    \
  _Pragma("unroll")                                                           \
  for (int ks = 0; ks < 2; ++ks) {                                            \
    f16x8 ahf[4], alf[4];                                                     \
    _Pragma("unroll")                                                         \
    for (int mt = 0; mt < 4; ++mt) {                                          \
      int off = (mt * 16 + l15) * 72 + ks * 32 + quad * 8;                    \
      ahf[mt] = *(const f16x8*)&Ah[BUF][off];                                 \
      if (SPLIT_A) alf[mt] = *(const f16x8*)&Al[BUF][off];                    \
    }                                                                         \
    _Pragma("unroll")                                                         \
    for (int mt = 0; mt < 4; ++mt)                                            \
      _Pragma("unroll")                                                       \
      for (int nt = 0; nt < 2; ++nt) {                                        \
        if (SPLIT_A)                                                          \
          acc[mt][nt] = __builtin_amdgcn_mfma_f32_16x16x32_f16(               \
              alf[mt], (BF)[ks][nt], acc[mt][nt], 0, 0, 0);                   \
        acc[mt][nt] = __builtin_amdgcn_mfma_f32_16x16x32_f16(                 \
            ahf[mt], (BF)[ks][nt], acc[mt][nt], 0, 0, 0);                     \
      }                                                                       \
  }

// ---- one pipelined k-step (R7 structure) ----
// entering: Ah[CUR] = A[KS]; BFC = B[KS]; XVC = x[KS+1] (reg).
// issue B[KS+1]->BFN, x[KS+2]->XVN; MFMA; eval+write A[KS+1] -> Ah[CUR^1].
#define KSTEP_BODY(KS, CUR, BFC, BFN, XVC, XVN)                               \
  {                                                                           \
    const int kp1 = ((KS) + 1 <= klast) ? (KS) + 1 : klast;                   \
    const int kp2 = ((KS) + 2 <= klast) ? (KS) + 2 : klast;                   \
    _Pragma("unroll")                                                         \
    for (int ks = 0; ks < 2; ++ks)                                            \
      _Pragma("unroll")                                                       \
      for (int nt = 0; nt < 2; ++nt)                                          \
        BFN[ks][nt] =                                                         \
            *(const f16x8*)&bbase[nt][(size_t)kp1 * 1024 + ks * 512];         \
    XVN = xrow[kp2 * 4];                                                      \
    MFMA_STEP(CUR, BFC);                                                      \
    EVAL_WRITE((CUR) ^ 1, XVC);                                               \
    __syncthreads();                                                          \
  }

  // ---- prologue: A[kbeg] into Ah[0]; B[kbeg] + x[kbeg+1] into regs ----
  f16x8 bf0[2][2], bf1[2][2];
#pragma unroll
  for (int ks = 0; ks < 2; ++ks)
#pragma unroll
    for (int nt = 0; nt < 2; ++nt)
      bf0[ks][nt] = *(const f16x8*)&bbase[nt][(size_t)kbeg * 1024 + ks * 512];
  float xvP = xrow[kbeg * 4];
  float xv0 = xrow[((kbeg + 1 <= klast) ? kbeg + 1 : klast) * 4];
  float xv1;
  EVAL_WRITE(0, xvP);
  __syncthreads();

  for (int k = kbeg; k < kend; k += 2) {
    KSTEP_BODY(k,     0, bf0, bf1, xv0, xv1);
    KSTEP_BODY(k + 1, 1, bf1, bf0, xv1, xv0);
  }

#undef KSTEP_BODY
#undef MFMA_STEP
#undef EVAL_WRITE

  // ---- epilogue: C/D layout col=lane&15, row=quad*4+reg; split-K atomics ----
#pragma unroll
  for (int mt = 0; mt < 4; ++mt)
#pragma unroll
    for (int nt = 0; nt < 2; ++nt) {
      int col = n0 + wn * 32 + nt * 16 + l15;
#pragma unroll
      for (int r = 0; r < 4; ++r) {
        int row = b0 + mt * 16 + quad * 4 + r;
        atomicAdd(&outp[(size_t)row * OUT + col], acc[mt][nt][r]);
      }
    }
}

// KL accumulation + f16 conversion + fragment-order swizzle, one pass over cm/lv.
// Group = 8 consecutive k of one output row o: dest Bsw[o/16][k/8][o%16][8].
__global__ __launch_bounds__(256) void kl_convert(
    const float* __restrict__ cm, const float* __restrict__ lv,
    ushort_t* __restrict__ bsw, int G /* = IN*2 groups per row */,
    long long ngroups, float* __restrict__ klout) {
  long long i = (long long)blockIdx.x * blockDim.x + threadIdx.x;
  const long long stride = (long long)gridDim.x * blockDim.x;
  float s = 0.0f;
  for (; i < ngroups; i += stride) {
    int o = (int)(i / G);
    int kc = (int)(i - (long long)o * G);
    const float* cp = &cm[i * 8];
    const float* lp = &lv[i * 8];
    unsigned pk[4];
#pragma unroll
    for (int t = 0; t < 4; ++t) {
      float c0 = cp[2 * t], c1 = cp[2 * t + 1];
      float l0 = lp[2 * t], l1 = lp[2 * t + 1];
      pk[t] = (unsigned)f2h(c0) | ((unsigned)f2h(c1) << 16);
      s += 0.5f * (__expf(l0) + c0 * c0 - 1.0f - l0);
      s += 0.5f * (__expf(l1) + c1 * c1 - 1.0f - l1);
    }
    uint4 v; v.x = pk[0]; v.y = pk[1]; v.z = pk[2]; v.w = pk[3];
    size_t doff = (((size_t)(o >> 4) * G + kc) * 16 + (o & 15)) * 8;
    *(uint4*)&bsw[doff] = v;
  }
#pragma unroll
  for (int off = 32; off > 0; off >>= 1) s += __shfl_down(s, off, 64);
  __shared__ float red[4];
  int wv = threadIdx.x >> 6;
  if ((threadIdx.x & 63) == 0) red[wv] = s;
  __syncthreads();
  if (threadIdx.x == 0)
    atomicAdd(klout, red[0] + red[1] + red[2] + red[3]);
}

extern "C" void kernel_launch(void* const* d_in, const int* in_sizes, int n_in,
                              void* d_out, int out_size, void* d_ws, size_t ws_size,
                              hipStream_t stream) {
  const float* x   = (const float*)d_in[0];
  const float* cm0 = (const float*)d_in[1];
  const float* lv0 = (const float*)d_in[2];
  const float* cm1 = (const float*)d_in[3];
  const float* lv1 = (const float*)d_in[4];
  const float* cm2 = (const float*)d_in[5];
  const float* lv2 = (const float*)d_in[6];

  float* out = (float*)d_out;                       // (8192*256) out + 1 KL
  float* klp = out + (size_t)8192 * 256;

  // ws layout (48 MB): acts 2x16MB, swizzled f16 weights 16MB
  char* ws = (char*)d_ws;
  float*    act1 = (float*)(ws);                               // 8192*512 f32
  float*    act2 = (float*)(ws + ((size_t)16 << 20));          // 8192*512 f32
  ushort_t* b0sw = (ushort_t*)(ws + ((size_t)32 << 20));       // 512*256*16 f16
  ushort_t* b1sw = (ushort_t*)(ws + ((size_t)36 << 20));       // 512*512*16 f16
  ushort_t* b2sw = (ushort_t*)(ws + ((size_t)44 << 20));       // 256*512*16 f16

  // zero split-K accumulation targets (act1+act2 contiguous; d_out incl KL)
  hipMemsetAsync(ws, 0, (size_t)32 << 20, stream);
  hipMemsetAsync(d_out, 0, (size_t)out_size * sizeof(float), stream);

  kl_convert<<<2048, 256, 0, stream>>>(cm0, lv0, b0sw, 256 * 2, 512LL * 256 * 2, klp);
  kl_convert<<<2048, 256, 0, stream>>>(cm1, lv1, b1sw, 512 * 2, 512LL * 512 * 2, klp);
  kl_convert<<<2048, 256, 0, stream>>>(cm2, lv2, b2sw, 512 * 2, 256LL * 512 * 2, klp);

  // 2048/2048/2048 blocks; LDS: L0 36864 B, L1/L2 18432 B (4 blk/CU target)
  kan_layer<true ><<<dim3(128, 4, 4), 256, 0, stream>>>(x,    b0sw, act1, 256, 512);
  kan_layer<false><<<dim3(128, 4, 4), 256, 0, stream>>>(act1, b1sw, act2, 512, 512);
  kan_layer<false><<<dim3(128, 2, 8), 256, 0, stream>>>(act2, b2sw, out,  512, 256);
}